// Round 1
// baseline (3459.287 us; speedup 1.0000x reference)
//
#include <hip/hip_runtime.h>
#include <stdint.h>

#define C_INP 10
#define CH    64
#define WBEV  512
#define HBEV  512
#define BQ    4
#define WH    (WBEV*HBEV)
#define BN_EPS 1e-3f
#define WIN   224   // points per k_main block (LDS: 2*224*72*2 = 64512 B < 64 KB)

typedef unsigned short ushort8 __attribute__((ext_vector_type(8)));

__device__ __forceinline__ unsigned short f2b(float x) {   // fp32 -> bf16 RNE
  unsigned int u = __float_as_uint(x);
  return (unsigned short)((u + 0x7FFFu + ((u >> 16) & 1u)) >> 16);
}
__device__ __forceinline__ float b2f(unsigned short u) {
  return __uint_as_float(((unsigned int)u) << 16);
}

// ---- Pass 1: X first/second moments (65 accumulators) -----------------------
__global__ void k_stats(const float* __restrict__ X, int N, float* __restrict__ sums) {
  float a[65];
#pragma unroll
  for (int i = 0; i < 65; ++i) a[i] = 0.f;
  const int stride = gridDim.x * blockDim.x;
  for (int i = blockIdx.x * blockDim.x + threadIdx.x; i < N; i += stride) {
    const float* xr = X + (size_t)i * C_INP;
    float x[C_INP];
#pragma unroll
    for (int k = 0; k < C_INP; ++k) x[k] = xr[k];
#pragma unroll
    for (int k = 0; k < C_INP; ++k) a[k] += x[k];
    int ti = C_INP;
#pragma unroll
    for (int k = 0; k < C_INP; ++k)
#pragma unroll
      for (int l = k; l < C_INP; ++l) a[ti++] += x[k] * x[l];
  }
#pragma unroll
  for (int i = 0; i < 65; ++i) {
    float v = a[i];
    for (int o = 32; o > 0; o >>= 1) v += __shfl_down(v, o, 64);
    if ((threadIdx.x & 63) == 0) atomicAdd(&sums[i], v);
  }
}

// ---- Fold BN into W0', b0' --------------------------------------------------
__global__ void k_bnfold(const float* __restrict__ sums, const float* __restrict__ W0,
                         const float* __restrict__ gamma, const float* __restrict__ beta,
                         float Nf, float* __restrict__ W0p, float* __restrict__ b0p) {
  const int c = threadIdx.x;  // 64
  float w[C_INP];
#pragma unroll
  for (int k = 0; k < C_INP; ++k) w[k] = W0[k * CH + c];
  float mu = 0.f;
#pragma unroll
  for (int k = 0; k < C_INP; ++k) mu += (sums[k] / Nf) * w[k];
  float ex2 = 0.f;
  int ti = C_INP;
#pragma unroll
  for (int k = 0; k < C_INP; ++k)
#pragma unroll
    for (int l = k; l < C_INP; ++l) {
      const float s = sums[ti++] / Nf;
      ex2 += (k == l ? w[k] * w[k] : 2.f * w[k] * w[l]) * s;
    }
  const float var = ex2 - mu * mu;
  const float sc = gamma[c] * rsqrtf(var + BN_EPS);
#pragma unroll
  for (int k = 0; k < C_INP; ++k) W0p[k * CH + c] = w[k] * sc;
  b0p[c] = beta[c] - mu * sc;
}

// ---- CSR build --------------------------------------------------------------
__global__ void k_count(const int* __restrict__ idx, int N, int* __restrict__ counts) {
  const int i = blockIdx.x * 256 + threadIdx.x;
  if (i < N) atomicAdd(&counts[idx[i]], 1);
}

__global__ void k_scan(const int* __restrict__ counts, int M, int N,
                       int* __restrict__ off, int* __restrict__ head) {
  __shared__ int lds[1024];
  const int t = threadIdx.x;
  const int per = (M + 1023) >> 10;
  const int s0 = t * per;
  const int s1 = min(s0 + per, M);
  int sum = 0;
  for (int i = s0; i < s1; ++i) sum += counts[i];
  lds[t] = sum;
  __syncthreads();
  for (int o = 1; o < 1024; o <<= 1) {
    const int v = (t >= o) ? lds[t - o] : 0;
    __syncthreads();
    lds[t] += v;
    __syncthreads();
  }
  int run = lds[t] - sum;  // exclusive prefix
  for (int i = s0; i < s1; ++i) {
    off[i] = run; head[i] = run;
    run += counts[i];
  }
  if (t == 1023) off[M] = N;
}

__global__ void k_fill(const int* __restrict__ idx, int N, int* __restrict__ head,
                       int* __restrict__ plist, int* __restrict__ spil) {
  const int i = blockIdx.x * 256 + threadIdx.x;
  if (i < N) {
    const int p = idx[i];
    const int pos = atomicAdd(&head[p], 1);
    plist[pos] = i;
    spil[pos] = p;
  }
}

// ---- inverse map cell -> pillar --------------------------------------------
__global__ void k_invmap(const int* __restrict__ pind, int M, int* __restrict__ inv) {
  const int p = blockIdx.x * 256 + threadIdx.x;
  if (p < M) {
    const int b = pind[3 * p], x = pind[3 * p + 1], y = pind[3 * p + 2];
    inv[(size_t)b * WH + x * HBEV + y] = p;
  }
}

// ---- main fused kernel: h, s, exp, per-pillar reductions --------------------
__global__ __launch_bounds__(256, 2)
void k_main(const float* __restrict__ X,
            const int* __restrict__ plist, const int* __restrict__ spil,
            const int* __restrict__ off,
            const float* __restrict__ W0p, const float* __restrict__ b0p,
            const float* __restrict__ Ws, const float* __restrict__ bs,
            float* __restrict__ num, float* __restrict__ den, float* __restrict__ hmx,
            int N, int M) {
  __shared__ unsigned short sm[2 * WIN * 72];
  unsigned short* hB = sm;               // [WIN][72] bf16 h
  unsigned short* eB = sm + WIN * 72;    // [WIN][72] bf16 e=exp(s)
  const int t = threadIdx.x;
  const int w0 = blockIdx.x * WIN;
  const int w1 = min(w0 + WIN, N);

  if (t < WIN && w0 + t < N) {
    const int pid = plist[w0 + t];
    const float* xr = X + (size_t)pid * C_INP;
    float x[C_INP];
#pragma unroll
    for (int k = 0; k < C_INP; ++k) x[k] = xr[k];
    float h[CH];
#pragma unroll
    for (int c = 0; c < CH; ++c) {
      float a = b0p[c];
#pragma unroll
      for (int k = 0; k < C_INP; ++k) a = fmaf(x[k], W0p[k * CH + c], a);
      h[c] = fmaxf(a, 0.f);
    }
    {
      ushort8* dst = (ushort8*)(hB + t * 72);
#pragma unroll
      for (int i = 0; i < 8; ++i) {
        ushort8 v;
#pragma unroll
        for (int j = 0; j < 8; ++j) v[j] = f2b(h[i * 8 + j]);
        dst[i] = v;
      }
    }
    for (int c0 = 0; c0 < CH; c0 += 16) {
      float s[16];
#pragma unroll
      for (int j = 0; j < 16; ++j) s[j] = bs[c0 + j];
#pragma unroll
      for (int k = 0; k < CH; ++k) {
        const float hk = h[k];
#pragma unroll
        for (int j = 0; j < 16; ++j) s[j] = fmaf(hk, Ws[k * CH + c0 + j], s[j]);
      }
      ushort8* dst = (ushort8*)(eB + t * 72 + c0);
#pragma unroll
      for (int i = 0; i < 2; ++i) {
        ushort8 v;
#pragma unroll
        for (int j = 0; j < 8; ++j) v[j] = f2b(__expf(fmaxf(s[i * 8 + j], 0.f)));
        dst[i] = v;
      }
    }
  }
  __syncthreads();

  // phase 2: lane = channel, wave picks pillars round-robin
  const int wv = t >> 6, c = t & 63;
  const int pfirst = spil[w0];
  const int plast  = spil[w1 - 1];
  for (int p = pfirst + wv; p <= plast; p += 4) {
    const int l2 = max(off[p], w0) - w0;
    const int h2 = min(off[p + 1], w1) - w0;
    if (h2 <= l2) continue;
    float dn = 0.f, nm = 0.f, hm = 0.f;
    for (int r = l2; r < h2; ++r) {
      const float hv = b2f(hB[r * 72 + c]);
      const float ev = b2f(eB[r * 72 + c]);
      dn += ev;
      nm = fmaf(hv, ev, nm);
      hm = fmaxf(hm, hv);
    }
    const size_t o = (size_t)p * CH + c;
    atomicAdd(num + o, nm);
    atomicAdd(den + o, dn);
    atomicMax((int*)hmx + o, __float_as_int(hm));  // hm >= 0: int order == float order
  }
}

// ---- canvas gather with fused finalize -------------------------------------
__global__ __launch_bounds__(256)
void k_canvas(const int* __restrict__ inv, const float* __restrict__ num,
              const float* __restrict__ den, const float* __restrict__ hmx,
              float* __restrict__ out) {
  const int t = threadIdx.x;
  const int bid = blockIdx.x;                 // BQ*WBEV*2
  const int half = bid & 1;
  const int x = (bid >> 1) & (WBEV - 1);
  const int b = bid >> 10;
  const int ybase = half * 256;
  const size_t cell = (size_t)b * WH + (size_t)x * HBEV + ybase + t;
  const int iv = inv[cell];
  const size_t obase = (size_t)b * ((size_t)CH * WH) + (size_t)x * HBEV + ybase + t;
  if (iv >= 0) {
    const float4* np = (const float4*)(num + (size_t)iv * CH);
    const float4* dp = (const float4*)(den + (size_t)iv * CH);
    const float4* mp = (const float4*)(hmx + (size_t)iv * CH);
#pragma unroll 4
    for (int cq = 0; cq < 16; ++cq) {
      const float4 n = np[cq], d = dp[cq], m = mp[cq];
      out[obase + (size_t)(4 * cq + 0) * WH] = 0.5f * (n.x / d.x + m.x);
      out[obase + (size_t)(4 * cq + 1) * WH] = 0.5f * (n.y / d.y + m.y);
      out[obase + (size_t)(4 * cq + 2) * WH] = 0.5f * (n.z / d.z + m.z);
      out[obase + (size_t)(4 * cq + 3) * WH] = 0.5f * (n.w / d.w + m.w);
    }
  } else {
#pragma unroll 8
    for (int cc = 0; cc < CH; ++cc) out[obase + (size_t)cc * WH] = 0.f;
  }
}

extern "C" void kernel_launch(void* const* d_in, const int* in_sizes, int n_in,
                              void* d_out, int out_size, void* d_ws, size_t ws_size,
                              hipStream_t stream) {
  const float* X     = (const float*)d_in[0];
  const int*   idx   = (const int*)  d_in[1];
  const int*   pind  = (const int*)  d_in[2];
  const float* W0    = (const float*)d_in[3];
  const float* gamma = (const float*)d_in[4];
  const float* beta  = (const float*)d_in[5];
  const float* Ws    = (const float*)d_in[6];
  const float* bs    = (const float*)d_in[7];
  float* out = (float*)d_out;
  const int N = in_sizes[0] / C_INP;   // 2,000,000
  const int M = in_sizes[2] / 3;       // 200,000

  char* p = (char*)d_ws;
  auto carve = [&](size_t bytes) -> char* {
    char* r = p;
    p += (bytes + 255) & ~(size_t)255;
    return r;
  };
  int*   counts = (int*)  carve((size_t)M * 4);
  int*   off    = (int*)  carve((size_t)(M + 1) * 4);
  int*   head   = (int*)  carve((size_t)M * 4);
  int*   plist  = (int*)  carve((size_t)N * 4);
  int*   spil   = (int*)  carve((size_t)N * 4);
  float* sums   = (float*)carve(65 * 4);
  float* W0p    = (float*)carve((size_t)C_INP * CH * 4);
  float* b0p    = (float*)carve((size_t)CH * 4);
  float* num    = (float*)carve((size_t)M * CH * 4);   // these three are contiguous
  float* den    = (float*)carve((size_t)M * CH * 4);
  float* hmx    = (float*)carve((size_t)M * CH * 4);
  int*   inv    = (int*)  carve((size_t)BQ * WH * 4);

  hipMemsetAsync(counts, 0, (size_t)M * 4, stream);
  hipMemsetAsync(sums, 0, 65 * 4, stream);
  hipMemsetAsync(num, 0, (size_t)M * CH * 4 * 3, stream);   // num+den+hmx
  hipMemsetAsync(inv, 0xFF, (size_t)BQ * WH * 4, stream);   // -1

  k_stats <<<1024, 256, 0, stream>>>(X, N, sums);
  k_bnfold<<<1, 64, 0, stream>>>(sums, W0, gamma, beta, (float)N, W0p, b0p);
  k_count <<<(N + 255) / 256, 256, 0, stream>>>(idx, N, counts);
  k_scan  <<<1, 1024, 0, stream>>>(counts, M, N, off, head);
  k_fill  <<<(N + 255) / 256, 256, 0, stream>>>(idx, N, head, plist, spil);
  k_invmap<<<(M + 255) / 256, 256, 0, stream>>>(pind, M, inv);
  k_main  <<<(N + WIN - 1) / WIN, 256, 0, stream>>>(X, plist, spil, off, W0p, b0p,
                                                    Ws, bs, num, den, hmx, N, M);
  k_canvas<<<BQ * WBEV * 2, 256, 0, stream>>>(inv, num, den, hmx, out);
}

// Round 2
// 1636.593 us; speedup vs baseline: 2.1137x; 2.1137x over previous
//
#include <hip/hip_runtime.h>
#include <stdint.h>

#define C_INP 10
#define CH    64
#define WBEV  512
#define HBEV  512
#define BQ    4
#define WH    (WBEV*HBEV)
#define BN_EPS 1e-3f
#define WIN   224   // points per k_main block (LDS: 2*224*72*2 = 64512 B < 64 KB)

typedef unsigned short ushort8 __attribute__((ext_vector_type(8)));

__device__ __forceinline__ unsigned short f2b(float x) {   // fp32 -> bf16 RNE
  unsigned int u = __float_as_uint(x);
  return (unsigned short)((u + 0x7FFFu + ((u >> 16) & 1u)) >> 16);
}
__device__ __forceinline__ float b2f(unsigned short u) {
  return __uint_as_float(((unsigned int)u) << 16);
}

// ---- Pass 1: X first/second moments (65 accumulators, all static-indexed) ---
// triangle index for pair (k,l), l>=k:  10 + k*(21-k)/2 + (l-k)
__global__ __launch_bounds__(256, 1)
void k_stats(const float* __restrict__ X, int N, float* __restrict__ sums) {
  float a[65];
#pragma unroll
  for (int i = 0; i < 65; ++i) a[i] = 0.f;
  const int stride = gridDim.x * blockDim.x;
  for (int i = blockIdx.x * blockDim.x + threadIdx.x; i < N; i += stride) {
    const float* xr = X + (size_t)i * C_INP;
    float x[C_INP];
#pragma unroll
    for (int k = 0; k < C_INP; ++k) x[k] = xr[k];
#pragma unroll
    for (int k = 0; k < C_INP; ++k) a[k] += x[k];
#pragma unroll
    for (int k = 0; k < C_INP; ++k)
#pragma unroll
      for (int l = k; l < C_INP; ++l)
        a[C_INP + (k * (21 - k)) / 2 + (l - k)] = fmaf(x[k], x[l], a[C_INP + (k * (21 - k)) / 2 + (l - k)]);
  }
  __shared__ float red[4 * 65];
  const int wv = threadIdx.x >> 6;
#pragma unroll
  for (int i = 0; i < 65; ++i) {
    float v = a[i];
    v += __shfl_down(v, 32, 64);
    v += __shfl_down(v, 16, 64);
    v += __shfl_down(v, 8, 64);
    v += __shfl_down(v, 4, 64);
    v += __shfl_down(v, 2, 64);
    v += __shfl_down(v, 1, 64);
    if ((threadIdx.x & 63) == 0) red[wv * 65 + i] = v;
  }
  __syncthreads();
  const int t = threadIdx.x;
  if (t < 65) atomicAdd(&sums[t], red[t] + red[65 + t] + red[130 + t] + red[195 + t]);
}

// ---- Fold BN into W0', b0' --------------------------------------------------
__global__ void k_bnfold(const float* __restrict__ sums, const float* __restrict__ W0,
                         const float* __restrict__ gamma, const float* __restrict__ beta,
                         float Nf, float* __restrict__ W0p, float* __restrict__ b0p) {
  const int c = threadIdx.x;  // 64
  float w[C_INP];
#pragma unroll
  for (int k = 0; k < C_INP; ++k) w[k] = W0[k * CH + c];
  float mu = 0.f;
#pragma unroll
  for (int k = 0; k < C_INP; ++k) mu += (sums[k] / Nf) * w[k];
  float ex2 = 0.f;
  int ti = C_INP;
#pragma unroll
  for (int k = 0; k < C_INP; ++k)
#pragma unroll
    for (int l = k; l < C_INP; ++l) {
      const float s = sums[ti++] / Nf;
      ex2 += (k == l ? w[k] * w[k] : 2.f * w[k] * w[l]) * s;
    }
  const float var = ex2 - mu * mu;
  const float sc = gamma[c] * rsqrtf(var + BN_EPS);
#pragma unroll
  for (int k = 0; k < C_INP; ++k) W0p[k * CH + c] = w[k] * sc;
  b0p[c] = beta[c] - mu * sc;
}

// ---- CSR build --------------------------------------------------------------
__global__ void k_count(const int* __restrict__ idx, int N, int* __restrict__ counts) {
  const int i = blockIdx.x * 256 + threadIdx.x;
  if (i < N) atomicAdd(&counts[idx[i]], 1);
}

__global__ void k_scan(const int* __restrict__ counts, int M, int N,
                       int* __restrict__ off, int* __restrict__ head) {
  __shared__ int lds[1024];
  const int t = threadIdx.x;
  const int per = (M + 1023) >> 10;
  const int s0 = t * per;
  const int s1 = min(s0 + per, M);
  int sum = 0;
  for (int i = s0; i < s1; ++i) sum += counts[i];
  lds[t] = sum;
  __syncthreads();
  for (int o = 1; o < 1024; o <<= 1) {
    const int v = (t >= o) ? lds[t - o] : 0;
    __syncthreads();
    lds[t] += v;
    __syncthreads();
  }
  int run = lds[t] - sum;  // exclusive prefix
  for (int i = s0; i < s1; ++i) {
    off[i] = run; head[i] = run;
    run += counts[i];
  }
  if (t == 1023) off[M] = N;
}

__global__ void k_fill(const int* __restrict__ idx, int N, int* __restrict__ head,
                       int* __restrict__ plist) {
  const int i = blockIdx.x * 256 + threadIdx.x;
  if (i < N) {
    const int p = idx[i];
    const int pos = atomicAdd(&head[p], 1);
    plist[pos] = i;
  }
}

// ---- inverse map cell -> pillar --------------------------------------------
__global__ void k_invmap(const int* __restrict__ pind, int M, int* __restrict__ inv) {
  const int p = blockIdx.x * 256 + threadIdx.x;
  if (p < M) {
    const int b = pind[3 * p], x = pind[3 * p + 1], y = pind[3 * p + 2];
    inv[(size_t)b * WH + x * HBEV + y] = p;
  }
}

// ---- main fused kernel: h, s, exp, per-pillar reductions --------------------
__global__ __launch_bounds__(256, 2)
void k_main(const float* __restrict__ X,
            const int* __restrict__ plist, const int* __restrict__ idx,
            const int* __restrict__ off,
            const float* __restrict__ W0p, const float* __restrict__ b0p,
            const float* __restrict__ Ws, const float* __restrict__ bs,
            float* __restrict__ num, float* __restrict__ den, float* __restrict__ hmx,
            int N, int M) {
  __shared__ unsigned short sm[2 * WIN * 72];
  unsigned short* hB = sm;               // [WIN][72] bf16 h
  unsigned short* eB = sm + WIN * 72;    // [WIN][72] bf16 e=exp(s)
  const int t = threadIdx.x;
  const int w0 = blockIdx.x * WIN;
  const int w1 = min(w0 + WIN, N);

  if (t < WIN && w0 + t < N) {
    const int pid = plist[w0 + t];
    const float* xr = X + (size_t)pid * C_INP;
    float x[C_INP];
#pragma unroll
    for (int k = 0; k < C_INP; ++k) x[k] = xr[k];
    float h[CH];
#pragma unroll
    for (int c = 0; c < CH; ++c) {
      float a = b0p[c];
#pragma unroll
      for (int k = 0; k < C_INP; ++k) a = fmaf(x[k], W0p[k * CH + c], a);
      h[c] = fmaxf(a, 0.f);
    }
    {
      ushort8* dst = (ushort8*)(hB + t * 72);
#pragma unroll
      for (int i = 0; i < 8; ++i) {
        ushort8 v;
#pragma unroll
        for (int j = 0; j < 8; ++j) v[j] = f2b(h[i * 8 + j]);
        dst[i] = v;
      }
    }
    for (int c0 = 0; c0 < CH; c0 += 16) {
      float s[16];
#pragma unroll
      for (int j = 0; j < 16; ++j) s[j] = bs[c0 + j];
#pragma unroll
      for (int k = 0; k < CH; ++k) {
        const float hk = h[k];
#pragma unroll
        for (int j = 0; j < 16; ++j) s[j] = fmaf(hk, Ws[k * CH + c0 + j], s[j]);
      }
      ushort8* dst = (ushort8*)(eB + t * 72 + c0);
#pragma unroll
      for (int i = 0; i < 2; ++i) {
        ushort8 v;
#pragma unroll
        for (int j = 0; j < 8; ++j) v[j] = f2b(__expf(fmaxf(s[i * 8 + j], 0.f)));
        dst[i] = v;
      }
    }
  }
  __syncthreads();

  // phase 2: lane = channel, wave picks pillars round-robin
  const int wv = t >> 6, c = t & 63;
  const int pfirst = idx[plist[w0]];
  const int plast  = idx[plist[w1 - 1]];
  for (int p = pfirst + wv; p <= plast; p += 4) {
    const int pb = off[p], pe = off[p + 1];
    const int l2 = max(pb, w0) - w0;
    const int h2 = min(pe, w1) - w0;
    if (h2 <= l2) continue;
    float dn = 0.f, nm = 0.f, hm = 0.f;
    for (int r = l2; r < h2; ++r) {
      const float hv = b2f(hB[r * 72 + c]);
      const float ev = b2f(eB[r * 72 + c]);
      dn += ev;
      nm = fmaf(hv, ev, nm);
      hm = fmaxf(hm, hv);
    }
    const size_t o = (size_t)p * CH + c;
    if (pb >= w0 && pe <= w1) {          // sole writer: plain stores
      num[o] = nm; den[o] = dn; hmx[o] = hm;
    } else {                              // window-boundary pillar: accumulate
      atomicAdd(num + o, nm);
      atomicAdd(den + o, dn);
      atomicMax((int*)hmx + o, __float_as_int(hm));  // hm >= 0: int order == float order
    }
  }
}

// ---- canvas gather with fused finalize -------------------------------------
__global__ __launch_bounds__(256)
void k_canvas(const int* __restrict__ inv, const float* __restrict__ num,
              const float* __restrict__ den, const float* __restrict__ hmx,
              float* __restrict__ out) {
  const int t = threadIdx.x;
  const int bid = blockIdx.x;                 // BQ*WBEV*2
  const int half = bid & 1;
  const int x = (bid >> 1) & (WBEV - 1);
  const int b = bid >> 10;
  const int ybase = half * 256;
  const size_t cell = (size_t)b * WH + (size_t)x * HBEV + ybase + t;
  const int iv = inv[cell];
  const size_t obase = (size_t)b * ((size_t)CH * WH) + (size_t)x * HBEV + ybase + t;
  if (iv >= 0) {
    const float4* np = (const float4*)(num + (size_t)iv * CH);
    const float4* dp = (const float4*)(den + (size_t)iv * CH);
    const float4* mp = (const float4*)(hmx + (size_t)iv * CH);
#pragma unroll 4
    for (int cq = 0; cq < 16; ++cq) {
      const float4 n = np[cq], d = dp[cq], m = mp[cq];
      out[obase + (size_t)(4 * cq + 0) * WH] = 0.5f * (n.x / d.x + m.x);
      out[obase + (size_t)(4 * cq + 1) * WH] = 0.5f * (n.y / d.y + m.y);
      out[obase + (size_t)(4 * cq + 2) * WH] = 0.5f * (n.z / d.z + m.z);
      out[obase + (size_t)(4 * cq + 3) * WH] = 0.5f * (n.w / d.w + m.w);
    }
  } else {
#pragma unroll 8
    for (int cc = 0; cc < CH; ++cc) out[obase + (size_t)cc * WH] = 0.f;
  }
}

extern "C" void kernel_launch(void* const* d_in, const int* in_sizes, int n_in,
                              void* d_out, int out_size, void* d_ws, size_t ws_size,
                              hipStream_t stream) {
  const float* X     = (const float*)d_in[0];
  const int*   idx   = (const int*)  d_in[1];
  const int*   pind  = (const int*)  d_in[2];
  const float* W0    = (const float*)d_in[3];
  const float* gamma = (const float*)d_in[4];
  const float* beta  = (const float*)d_in[5];
  const float* Ws    = (const float*)d_in[6];
  const float* bs    = (const float*)d_in[7];
  float* out = (float*)d_out;
  const int N = in_sizes[0] / C_INP;   // 2,000,000
  const int M = in_sizes[2] / 3;       // 200,000

  char* p = (char*)d_ws;
  auto carve = [&](size_t bytes) -> char* {
    char* r = p;
    p += (bytes + 255) & ~(size_t)255;
    return r;
  };
  int*   counts = (int*)  carve((size_t)M * 4);
  int*   off    = (int*)  carve((size_t)(M + 1) * 4);
  int*   head   = (int*)  carve((size_t)M * 4);
  int*   plist  = (int*)  carve((size_t)N * 4);
  float* sums   = (float*)carve(65 * 4);
  float* W0p    = (float*)carve((size_t)C_INP * CH * 4);
  float* b0p    = (float*)carve((size_t)CH * 4);
  float* num    = (float*)carve((size_t)M * CH * 4);   // these three are contiguous
  float* den    = (float*)carve((size_t)M * CH * 4);
  float* hmx    = (float*)carve((size_t)M * CH * 4);
  int*   inv    = (int*)  carve((size_t)BQ * WH * 4);

  hipMemsetAsync(counts, 0, (size_t)M * 4, stream);
  hipMemsetAsync(sums, 0, 65 * 4, stream);
  hipMemsetAsync(num, 0, (size_t)M * CH * 4 * 3, stream);   // num+den+hmx
  hipMemsetAsync(inv, 0xFF, (size_t)BQ * WH * 4, stream);   // -1

  k_stats <<<512, 256, 0, stream>>>(X, N, sums);
  k_bnfold<<<1, 64, 0, stream>>>(sums, W0, gamma, beta, (float)N, W0p, b0p);
  k_count <<<(N + 255) / 256, 256, 0, stream>>>(idx, N, counts);
  k_scan  <<<1, 1024, 0, stream>>>(counts, M, N, off, head);
  k_fill  <<<(N + 255) / 256, 256, 0, stream>>>(idx, N, head, plist);
  k_invmap<<<(M + 255) / 256, 256, 0, stream>>>(pind, M, inv);
  k_main  <<<(N + WIN - 1) / WIN, 256, 0, stream>>>(X, plist, idx, off, W0p, b0p,
                                                    Ws, bs, num, den, hmx, N, M);
  k_canvas<<<BQ * WBEV * 2, 256, 0, stream>>>(inv, num, den, hmx, out);
}

// Round 3
// 1407.269 us; speedup vs baseline: 2.4582x; 1.1630x over previous
//
#include <hip/hip_runtime.h>
#include <stdint.h>

#define C_INP 10
#define CH    64
#define WBEV  512
#define HBEV  512
#define BQ    4
#define WH    (WBEV*HBEV)
#define BN_EPS 1e-3f
#define WIN   224   // points per k_main block (LDS: 2*224*72*2 = 64512 B < 64 KB)

typedef unsigned short ushort8 __attribute__((ext_vector_type(8)));
typedef short  bf16x8 __attribute__((ext_vector_type(8)));
typedef float  f32x4  __attribute__((ext_vector_type(4)));

__device__ __forceinline__ unsigned short f2b(float x) {   // fp32 -> bf16 RNE
  unsigned int u = __float_as_uint(x);
  return (unsigned short)((u + 0x7FFFu + ((u >> 16) & 1u)) >> 16);
}
__device__ __forceinline__ float b2f(unsigned short u) {
  return __uint_as_float(((unsigned int)u) << 16);
}

// ---- Pass 1: X first/second moments (65 accumulators, all static-indexed) ---
__global__ __launch_bounds__(256, 1)
void k_stats(const float* __restrict__ X, int N, float* __restrict__ sums) {
  float a[65];
#pragma unroll
  for (int i = 0; i < 65; ++i) a[i] = 0.f;
  const int stride = gridDim.x * blockDim.x;
  for (int i = blockIdx.x * blockDim.x + threadIdx.x; i < N; i += stride) {
    const float* xr = X + (size_t)i * C_INP;
    float x[C_INP];
#pragma unroll
    for (int k = 0; k < C_INP; ++k) x[k] = xr[k];
#pragma unroll
    for (int k = 0; k < C_INP; ++k) a[k] += x[k];
#pragma unroll
    for (int k = 0; k < C_INP; ++k)
#pragma unroll
      for (int l = k; l < C_INP; ++l)
        a[C_INP + (k * (21 - k)) / 2 + (l - k)] = fmaf(x[k], x[l], a[C_INP + (k * (21 - k)) / 2 + (l - k)]);
  }
  __shared__ float red[4 * 65];
  const int wv = threadIdx.x >> 6;
#pragma unroll
  for (int i = 0; i < 65; ++i) {
    float v = a[i];
    v += __shfl_down(v, 32, 64);
    v += __shfl_down(v, 16, 64);
    v += __shfl_down(v, 8, 64);
    v += __shfl_down(v, 4, 64);
    v += __shfl_down(v, 2, 64);
    v += __shfl_down(v, 1, 64);
    if ((threadIdx.x & 63) == 0) red[wv * 65 + i] = v;
  }
  __syncthreads();
  const int t = threadIdx.x;
  if (t < 65) atomicAdd(&sums[t], red[t] + red[65 + t] + red[130 + t] + red[195 + t]);
}

// ---- Fold BN into W0', b0' --------------------------------------------------
__global__ void k_bnfold(const float* __restrict__ sums, const float* __restrict__ W0,
                         const float* __restrict__ gamma, const float* __restrict__ beta,
                         float Nf, float* __restrict__ W0p, float* __restrict__ b0p) {
  const int c = threadIdx.x;  // 64
  float w[C_INP];
#pragma unroll
  for (int k = 0; k < C_INP; ++k) w[k] = W0[k * CH + c];
  float mu = 0.f;
#pragma unroll
  for (int k = 0; k < C_INP; ++k) mu += (sums[k] / Nf) * w[k];
  float ex2 = 0.f;
  int ti = C_INP;
#pragma unroll
  for (int k = 0; k < C_INP; ++k)
#pragma unroll
    for (int l = k; l < C_INP; ++l) {
      const float s = sums[ti++] / Nf;
      ex2 += (k == l ? w[k] * w[k] : 2.f * w[k] * w[l]) * s;
    }
  const float var = ex2 - mu * mu;
  const float sc = gamma[c] * rsqrtf(var + BN_EPS);
#pragma unroll
  for (int k = 0; k < C_INP; ++k) W0p[k * CH + c] = w[k] * sc;
  b0p[c] = beta[c] - mu * sc;
}

// ---- CSR build --------------------------------------------------------------
__global__ void k_count(const int* __restrict__ idx, int N, int* __restrict__ counts) {
  const int i = blockIdx.x * 256 + threadIdx.x;
  if (i < N) atomicAdd(&counts[idx[i]], 1);
}

__global__ void k_scan(const int* __restrict__ counts, int M, int N,
                       int* __restrict__ off, int* __restrict__ head) {
  __shared__ int lds[1024];
  const int t = threadIdx.x;
  const int per = (M + 1023) >> 10;
  const int s0 = t * per;
  const int s1 = min(s0 + per, M);
  int sum = 0;
  for (int i = s0; i < s1; ++i) sum += counts[i];
  lds[t] = sum;
  __syncthreads();
  for (int o = 1; o < 1024; o <<= 1) {
    const int v = (t >= o) ? lds[t - o] : 0;
    __syncthreads();
    lds[t] += v;
    __syncthreads();
  }
  int run = lds[t] - sum;  // exclusive prefix
  for (int i = s0; i < s1; ++i) {
    off[i] = run; head[i] = run;
    run += counts[i];
  }
  if (t == 1023) off[M] = N;
}

__global__ void k_fill(const int* __restrict__ idx, int N, int* __restrict__ head,
                       int* __restrict__ plist) {
  const int i = blockIdx.x * 256 + threadIdx.x;
  if (i < N) {
    const int p = idx[i];
    const int pos = atomicAdd(&head[p], 1);
    plist[pos] = i;
  }
}

// ---- zero only window-boundary pillar rows (atomics targets) ----------------
__global__ __launch_bounds__(64)
void k_zb(const int* __restrict__ idx, const int* __restrict__ plist, int N,
          float* __restrict__ num, float* __restrict__ den, float* __restrict__ hmx) {
  const int b = blockIdx.x;
  const int c = threadIdx.x;
  const int w0 = b * WIN;
  const int w1 = min(w0 + WIN, N);
  const int p0 = idx[plist[w0]];
  const int p1 = idx[plist[w1 - 1]];
  const size_t o0 = (size_t)p0 * CH + c;
  const size_t o1 = (size_t)p1 * CH + c;
  num[o0] = 0.f; den[o0] = 0.f; hmx[o0] = 0.f;
  num[o1] = 0.f; den[o1] = 0.f; hmx[o1] = 0.f;
}

// ---- inverse map cell -> pillar --------------------------------------------
__global__ void k_invmap(const int* __restrict__ pind, int M, int* __restrict__ inv) {
  const int p = blockIdx.x * 256 + threadIdx.x;
  if (p < M) {
    const int b = pind[3 * p], x = pind[3 * p + 1], y = pind[3 * p + 2];
    inv[(size_t)b * WH + x * HBEV + y] = p;
  }
}

// ---- main fused kernel: h (VALU), s=h@Ws (MFMA), exp, per-pillar reductions -
__global__ __launch_bounds__(256, 2)
void k_main(const float* __restrict__ X,
            const int* __restrict__ plist, const int* __restrict__ idx,
            const int* __restrict__ off,
            const float* __restrict__ W0p, const float* __restrict__ b0p,
            const float* __restrict__ Ws, const float* __restrict__ bs,
            float* __restrict__ num, float* __restrict__ den, float* __restrict__ hmx,
            int N, int M) {
  __shared__ __attribute__((aligned(16))) unsigned short sm[2 * WIN * 72];
  unsigned short* hB = sm;               // [WIN][72] bf16 h
  unsigned short* eB = sm + WIN * 72;    // [WIN][72] bf16 e=exp(relu(s))
  const int t = threadIdx.x;
  const int w0 = blockIdx.x * WIN;
  const int w1 = min(w0 + WIN, N);

  // ---- phase 1a: per-point h = relu(X@W0' + b0')  (224 worker threads) ----
  if (t < WIN && w0 + t < N) {
    const int pid = plist[w0 + t];
    const float* xr = X + (size_t)pid * C_INP;
    float x[C_INP];
#pragma unroll
    for (int k = 0; k < C_INP; ++k) x[k] = xr[k];
    float h[CH];
#pragma unroll
    for (int c = 0; c < CH; ++c) {
      float a = b0p[c];
#pragma unroll
      for (int k = 0; k < C_INP; ++k) a = fmaf(x[k], W0p[k * CH + c], a);
      h[c] = fmaxf(a, 0.f);
    }
    ushort8* dst = (ushort8*)(hB + t * 72);
#pragma unroll
    for (int i = 0; i < 8; ++i) {
      ushort8 v;
#pragma unroll
      for (int j = 0; j < 8; ++j) v[j] = f2b(h[i * 8 + j]);
      dst[i] = v;
    }
  }

  // ---- B-fragments of Ws for this wave's channel tile (global, L2-hot) ----
  const int wv = t >> 6, lane = t & 63;
  const int l15 = lane & 15, quad = (lane >> 4) & 3;
  const int nCol = wv * 16 + l15;               // this wave's channel column
  bf16x8 bf0, bf1;
#pragma unroll
  for (int j = 0; j < 8; ++j) {
    bf0[j] = (short)f2b(Ws[(quad * 8 + j) * CH + nCol]);
    bf1[j] = (short)f2b(Ws[(32 + quad * 8 + j) * CH + nCol]);
  }
  const float bsv = bs[nCol];
  __syncthreads();

  // ---- phase 1b: s = h @ Ws via MFMA; e = exp(relu(s + bs)) -> eB ----------
#pragma unroll 2
  for (int mt = 0; mt < WIN / 16; ++mt) {       // 14 M-tiles, wave owns nt=wv
    const bf16x8 a0 = *(const bf16x8*)(hB + (mt * 16 + l15) * 72 + quad * 8);
    const bf16x8 a1 = *(const bf16x8*)(hB + (mt * 16 + l15) * 72 + 32 + quad * 8);
    f32x4 acc = {0.f, 0.f, 0.f, 0.f};
    acc = __builtin_amdgcn_mfma_f32_16x16x32_bf16(a0, bf0, acc, 0, 0, 0);
    acc = __builtin_amdgcn_mfma_f32_16x16x32_bf16(a1, bf1, acc, 0, 0, 0);
#pragma unroll
    for (int r = 0; r < 4; ++r) {
      const float e = __expf(fmaxf(acc[r] + bsv, 0.f));
      eB[(mt * 16 + quad * 4 + r) * 72 + nCol] = f2b(e);
    }
  }
  __syncthreads();

  // ---- phase 2: lane = channel, wave picks pillars round-robin -------------
  const int c = lane;
  const int pfirst = idx[plist[w0]];
  const int plast  = idx[plist[w1 - 1]];
  for (int p = pfirst + wv; p <= plast; p += 4) {
    const int pb = off[p], pe = off[p + 1];
    const int l2 = max(pb, w0) - w0;
    const int h2 = min(pe, w1) - w0;
    if (h2 <= l2) continue;
    float dn = 0.f, nm = 0.f, hm = 0.f;
    for (int r = l2; r < h2; ++r) {
      const float hv = b2f(hB[r * 72 + c]);
      const float ev = b2f(eB[r * 72 + c]);
      dn += ev;
      nm = fmaf(hv, ev, nm);
      hm = fmaxf(hm, hv);
    }
    const size_t o = (size_t)p * CH + c;
    if (pb >= w0 && pe <= w1) {          // sole writer: plain stores
      num[o] = nm; den[o] = dn; hmx[o] = hm;
    } else {                              // window-boundary pillar: accumulate
      atomicAdd(num + o, nm);
      atomicAdd(den + o, dn);
      atomicMax((int*)hmx + o, __float_as_int(hm));  // hm >= 0: int order == float order
    }
  }
}

// ---- canvas gather with fused finalize -------------------------------------
__global__ __launch_bounds__(256)
void k_canvas(const int* __restrict__ inv, const float* __restrict__ num,
              const float* __restrict__ den, const float* __restrict__ hmx,
              float* __restrict__ out) {
  const int t = threadIdx.x;
  const int bid = blockIdx.x;                 // BQ*WBEV*2
  const int half = bid & 1;
  const int x = (bid >> 1) & (WBEV - 1);
  const int b = bid >> 10;
  const int ybase = half * 256;
  const size_t cell = (size_t)b * WH + (size_t)x * HBEV + ybase + t;
  const int iv = inv[cell];
  const size_t obase = (size_t)b * ((size_t)CH * WH) + (size_t)x * HBEV + ybase + t;
  if (iv >= 0) {
    const float4* np = (const float4*)(num + (size_t)iv * CH);
    const float4* dp = (const float4*)(den + (size_t)iv * CH);
    const float4* mp = (const float4*)(hmx + (size_t)iv * CH);
#pragma unroll 4
    for (int cq = 0; cq < 16; ++cq) {
      const float4 n = np[cq], d = dp[cq], m = mp[cq];
      out[obase + (size_t)(4 * cq + 0) * WH] = 0.5f * (n.x / d.x + m.x);
      out[obase + (size_t)(4 * cq + 1) * WH] = 0.5f * (n.y / d.y + m.y);
      out[obase + (size_t)(4 * cq + 2) * WH] = 0.5f * (n.z / d.z + m.z);
      out[obase + (size_t)(4 * cq + 3) * WH] = 0.5f * (n.w / d.w + m.w);
    }
  } else {
#pragma unroll 8
    for (int cc = 0; cc < CH; ++cc) out[obase + (size_t)cc * WH] = 0.f;
  }
}

extern "C" void kernel_launch(void* const* d_in, const int* in_sizes, int n_in,
                              void* d_out, int out_size, void* d_ws, size_t ws_size,
                              hipStream_t stream) {
  const float* X     = (const float*)d_in[0];
  const int*   idx   = (const int*)  d_in[1];
  const int*   pind  = (const int*)  d_in[2];
  const float* W0    = (const float*)d_in[3];
  const float* gamma = (const float*)d_in[4];
  const float* beta  = (const float*)d_in[5];
  const float* Ws    = (const float*)d_in[6];
  const float* bs    = (const float*)d_in[7];
  float* out = (float*)d_out;
  const int N = in_sizes[0] / C_INP;   // 2,000,000
  const int M = in_sizes[2] / 3;       // 200,000
  const int nwin = (N + WIN - 1) / WIN;

  char* p = (char*)d_ws;
  auto carve = [&](size_t bytes) -> char* {
    char* r = p;
    p += (bytes + 255) & ~(size_t)255;
    return r;
  };
  int*   counts = (int*)  carve((size_t)M * 4);
  int*   off    = (int*)  carve((size_t)(M + 1) * 4);
  int*   head   = (int*)  carve((size_t)M * 4);
  int*   plist  = (int*)  carve((size_t)N * 4);
  float* sums   = (float*)carve(65 * 4);
  float* W0p    = (float*)carve((size_t)C_INP * CH * 4);
  float* b0p    = (float*)carve((size_t)CH * 4);
  float* num    = (float*)carve((size_t)M * CH * 4);
  float* den    = (float*)carve((size_t)M * CH * 4);
  float* hmx    = (float*)carve((size_t)M * CH * 4);
  int*   inv    = (int*)  carve((size_t)BQ * WH * 4);

  hipMemsetAsync(counts, 0, (size_t)M * 4, stream);
  hipMemsetAsync(sums, 0, 65 * 4, stream);
  hipMemsetAsync(inv, 0xFF, (size_t)BQ * WH * 4, stream);   // -1

  k_stats <<<1024, 256, 0, stream>>>(X, N, sums);
  k_bnfold<<<1, 64, 0, stream>>>(sums, W0, gamma, beta, (float)N, W0p, b0p);
  k_count <<<(N + 255) / 256, 256, 0, stream>>>(idx, N, counts);
  k_scan  <<<1, 1024, 0, stream>>>(counts, M, N, off, head);
  k_fill  <<<(N + 255) / 256, 256, 0, stream>>>(idx, N, head, plist);
  k_zb    <<<nwin, 64, 0, stream>>>(idx, plist, N, num, den, hmx);
  k_invmap<<<(M + 255) / 256, 256, 0, stream>>>(pind, M, inv);
  k_main  <<<nwin, 256, 0, stream>>>(X, plist, idx, off, W0p, b0p,
                                     Ws, bs, num, den, hmx, N, M);
  k_canvas<<<BQ * WBEV * 2, 256, 0, stream>>>(inv, num, den, hmx, out);
}

// Round 4
// 967.418 us; speedup vs baseline: 3.5758x; 1.4547x over previous
//
#include <hip/hip_runtime.h>
#include <stdint.h>

#define C_INP 10
#define CH    64
#define WBEV  512
#define HBEV  512
#define BQ    4
#define WH    (WBEV*HBEV)
#define BN_EPS 1e-3f
#define WIN   224     // points per k_main block (LDS: 2*224*72*2 = 64512 B < 64 KB)
#define SCHUNK 1024   // counts per scan block

typedef unsigned short ushort8 __attribute__((ext_vector_type(8)));
typedef short  bf16x8 __attribute__((ext_vector_type(8)));
typedef float  f32x4  __attribute__((ext_vector_type(4)));

__device__ __forceinline__ unsigned short f2b(float x) {   // fp32 -> bf16 RNE
  unsigned int u = __float_as_uint(x);
  return (unsigned short)((u + 0x7FFFu + ((u >> 16) & 1u)) >> 16);
}
__device__ __forceinline__ float b2f(unsigned short u) {
  return __uint_as_float(((unsigned int)u) << 16);
}

// ---- Pass 1: X first/second moments (65 accumulators, all static-indexed) ---
__global__ __launch_bounds__(256, 1)
void k_stats(const float* __restrict__ X, int N, float* __restrict__ sums) {
  float a[65];
#pragma unroll
  for (int i = 0; i < 65; ++i) a[i] = 0.f;
  const int stride = gridDim.x * blockDim.x;
  for (int i = blockIdx.x * blockDim.x + threadIdx.x; i < N; i += stride) {
    const float* xr = X + (size_t)i * C_INP;
    float x[C_INP];
#pragma unroll
    for (int k = 0; k < C_INP; ++k) x[k] = xr[k];
#pragma unroll
    for (int k = 0; k < C_INP; ++k) a[k] += x[k];
#pragma unroll
    for (int k = 0; k < C_INP; ++k)
#pragma unroll
      for (int l = k; l < C_INP; ++l)
        a[C_INP + (k * (21 - k)) / 2 + (l - k)] = fmaf(x[k], x[l], a[C_INP + (k * (21 - k)) / 2 + (l - k)]);
  }
  __shared__ float red[4 * 65];
  const int wv = threadIdx.x >> 6;
#pragma unroll
  for (int i = 0; i < 65; ++i) {
    float v = a[i];
    v += __shfl_down(v, 32, 64);
    v += __shfl_down(v, 16, 64);
    v += __shfl_down(v, 8, 64);
    v += __shfl_down(v, 4, 64);
    v += __shfl_down(v, 2, 64);
    v += __shfl_down(v, 1, 64);
    if ((threadIdx.x & 63) == 0) red[wv * 65 + i] = v;
  }
  __syncthreads();
  const int t = threadIdx.x;
  if (t < 65) atomicAdd(&sums[t], red[t] + red[65 + t] + red[130 + t] + red[195 + t]);
}

// ---- Fold BN into W0', b0' --------------------------------------------------
__global__ void k_bnfold(const float* __restrict__ sums, const float* __restrict__ W0,
                         const float* __restrict__ gamma, const float* __restrict__ beta,
                         float Nf, float* __restrict__ W0p, float* __restrict__ b0p) {
  const int c = threadIdx.x;  // 64
  float w[C_INP];
#pragma unroll
  for (int k = 0; k < C_INP; ++k) w[k] = W0[k * CH + c];
  float mu = 0.f;
#pragma unroll
  for (int k = 0; k < C_INP; ++k) mu += (sums[k] / Nf) * w[k];
  float ex2 = 0.f;
  int ti = C_INP;
#pragma unroll
  for (int k = 0; k < C_INP; ++k)
#pragma unroll
    for (int l = k; l < C_INP; ++l) {
      const float s = sums[ti++] / Nf;
      ex2 += (k == l ? w[k] * w[k] : 2.f * w[k] * w[l]) * s;
    }
  const float var = ex2 - mu * mu;
  const float sc = gamma[c] * rsqrtf(var + BN_EPS);
#pragma unroll
  for (int k = 0; k < C_INP; ++k) W0p[k * CH + c] = w[k] * sc;
  b0p[c] = beta[c] - mu * sc;
}

// ---- CSR build --------------------------------------------------------------
__global__ void k_count(const int* __restrict__ idx, int N, int* __restrict__ counts) {
  const int i = blockIdx.x * 256 + threadIdx.x;
  if (i < N) atomicAdd(&counts[idx[i]], 1);
}

// ---- multi-block exclusive scan of counts -> off/head -----------------------
__global__ __launch_bounds__(256)
void k_scan1(const int* __restrict__ counts, int M, int* __restrict__ bsum) {
  __shared__ int lds[256];
  const int b = blockIdx.x, t = threadIdx.x;
  const int base = b * SCHUNK + t * 4;
  int s = 0;
  if (base + 3 < M) {
    const int4 v = *(const int4*)(counts + base);
    s = v.x + v.y + v.z + v.w;
  } else {
#pragma unroll
    for (int j = 0; j < 4; ++j) if (base + j < M) s += counts[base + j];
  }
  lds[t] = s;
  __syncthreads();
  for (int o = 1; o < 256; o <<= 1) {
    const int u = (t >= o) ? lds[t - o] : 0;
    __syncthreads();
    lds[t] += u;
    __syncthreads();
  }
  if (t == 255) bsum[b] = lds[255];
}

__global__ __launch_bounds__(256)
void k_scan2(int* __restrict__ bsum, int nsb) {
  __shared__ int lds[256];
  const int t = threadIdx.x;
  const int v = (t < nsb) ? bsum[t] : 0;
  lds[t] = v;
  __syncthreads();
  for (int o = 1; o < 256; o <<= 1) {
    const int u = (t >= o) ? lds[t - o] : 0;
    __syncthreads();
    lds[t] += u;
    __syncthreads();
  }
  if (t < nsb) bsum[t] = lds[t] - v;   // exclusive base per scan block
}

__global__ __launch_bounds__(256)
void k_scan3(const int* __restrict__ counts, int M, int N,
             const int* __restrict__ bsum,
             int* __restrict__ off, int* __restrict__ head) {
  __shared__ int lds[256];
  const int b = blockIdx.x, t = threadIdx.x;
  const int base = b * SCHUNK + t * 4;
  int c0 = 0, c1 = 0, c2 = 0, c3 = 0;
  const bool full = (base + 3 < M);
  if (full) {
    const int4 v = *(const int4*)(counts + base);
    c0 = v.x; c1 = v.y; c2 = v.z; c3 = v.w;
  } else {
    if (base     < M) c0 = counts[base];
    if (base + 1 < M) c1 = counts[base + 1];
    if (base + 2 < M) c2 = counts[base + 2];
    if (base + 3 < M) c3 = counts[base + 3];
  }
  const int s = c0 + c1 + c2 + c3;
  lds[t] = s;
  __syncthreads();
  for (int o = 1; o < 256; o <<= 1) {
    const int u = (t >= o) ? lds[t - o] : 0;
    __syncthreads();
    lds[t] += u;
    __syncthreads();
  }
  const int run = bsum[b] + lds[t] - s;
  const int4 ov = {run, run + c0, run + c0 + c1, run + c0 + c1 + c2};
  if (full) {
    *(int4*)(off  + base) = ov;
    *(int4*)(head + base) = ov;
  } else {
    if (base     < M) { off[base]     = ov.x; head[base]     = ov.x; }
    if (base + 1 < M) { off[base + 1] = ov.y; head[base + 1] = ov.y; }
    if (base + 2 < M) { off[base + 2] = ov.z; head[base + 2] = ov.z; }
  }
  if (b == 0 && t == 0) off[M] = N;
}

__global__ void k_fill(const int* __restrict__ idx, int N, int* __restrict__ head,
                       int* __restrict__ plist) {
  const int i = blockIdx.x * 256 + threadIdx.x;
  if (i < N) {
    const int p = idx[i];
    const int pos = atomicAdd(&head[p], 1);
    plist[pos] = i;
  }
}

// ---- zero only window-boundary pillar rows (atomics targets) ----------------
__global__ __launch_bounds__(64)
void k_zb(const int* __restrict__ idx, const int* __restrict__ plist, int N,
          float* __restrict__ num, float* __restrict__ den, float* __restrict__ hmx) {
  const int b = blockIdx.x;
  const int c = threadIdx.x;
  const int w0 = b * WIN;
  const int w1 = min(w0 + WIN, N);
  const int p0 = idx[plist[w0]];
  const int p1 = idx[plist[w1 - 1]];
  const size_t o0 = (size_t)p0 * CH + c;
  const size_t o1 = (size_t)p1 * CH + c;
  num[o0] = 0.f; den[o0] = 0.f; hmx[o0] = 0.f;
  num[o1] = 0.f; den[o1] = 0.f; hmx[o1] = 0.f;
}

// ---- inverse map cell -> pillar --------------------------------------------
__global__ void k_invmap(const int* __restrict__ pind, int M, int* __restrict__ inv) {
  const int p = blockIdx.x * 256 + threadIdx.x;
  if (p < M) {
    const int b = pind[3 * p], x = pind[3 * p + 1], y = pind[3 * p + 2];
    inv[(size_t)b * WH + x * HBEV + y] = p;
  }
}

// ---- main fused kernel: h (VALU), s=h@Ws (MFMA), exp, per-pillar reductions -
__global__ __launch_bounds__(256, 2)
void k_main(const float* __restrict__ X,
            const int* __restrict__ plist, const int* __restrict__ idx,
            const int* __restrict__ off,
            const float* __restrict__ W0p, const float* __restrict__ b0p,
            const float* __restrict__ Ws, const float* __restrict__ bs,
            float* __restrict__ num, float* __restrict__ den, float* __restrict__ hmx,
            int N, int M) {
  __shared__ __attribute__((aligned(16))) unsigned short sm[2 * WIN * 72];
  unsigned short* hB = sm;               // [WIN][72] bf16 h
  unsigned short* eB = sm + WIN * 72;    // [WIN][72] bf16 e=exp(relu(s))
  const int t = threadIdx.x;
  const int w0 = blockIdx.x * WIN;
  const int w1 = min(w0 + WIN, N);

  // ---- phase 1a: per-point h = relu(X@W0' + b0')  (224 worker threads) ----
  if (t < WIN && w0 + t < N) {
    const int pid = plist[w0 + t];
    const float* xr = X + (size_t)pid * C_INP;
    float x[C_INP];
#pragma unroll
    for (int k = 0; k < C_INP; ++k) x[k] = xr[k];
    float h[CH];
#pragma unroll
    for (int c = 0; c < CH; ++c) {
      float a = b0p[c];
#pragma unroll
      for (int k = 0; k < C_INP; ++k) a = fmaf(x[k], W0p[k * CH + c], a);
      h[c] = fmaxf(a, 0.f);
    }
    ushort8* dst = (ushort8*)(hB + t * 72);
#pragma unroll
    for (int i = 0; i < 8; ++i) {
      ushort8 v;
#pragma unroll
      for (int j = 0; j < 8; ++j) v[j] = f2b(h[i * 8 + j]);
      dst[i] = v;
    }
  }

  // ---- B-fragments of Ws for this wave's channel tile (global, L2-hot) ----
  const int wv = t >> 6, lane = t & 63;
  const int l15 = lane & 15, quad = (lane >> 4) & 3;
  const int nCol = wv * 16 + l15;               // this wave's channel column
  bf16x8 bf0, bf1;
#pragma unroll
  for (int j = 0; j < 8; ++j) {
    bf0[j] = (short)f2b(Ws[(quad * 8 + j) * CH + nCol]);
    bf1[j] = (short)f2b(Ws[(32 + quad * 8 + j) * CH + nCol]);
  }
  const float bsv = bs[nCol];
  __syncthreads();

  // ---- phase 1b: s = h @ Ws via MFMA; e = exp(relu(s + bs)) -> eB ----------
#pragma unroll 2
  for (int mt = 0; mt < WIN / 16; ++mt) {       // 14 M-tiles, wave owns nt=wv
    const bf16x8 a0 = *(const bf16x8*)(hB + (mt * 16 + l15) * 72 + quad * 8);
    const bf16x8 a1 = *(const bf16x8*)(hB + (mt * 16 + l15) * 72 + 32 + quad * 8);
    f32x4 acc = {0.f, 0.f, 0.f, 0.f};
    acc = __builtin_amdgcn_mfma_f32_16x16x32_bf16(a0, bf0, acc, 0, 0, 0);
    acc = __builtin_amdgcn_mfma_f32_16x16x32_bf16(a1, bf1, acc, 0, 0, 0);
#pragma unroll
    for (int r = 0; r < 4; ++r) {
      const float e = __expf(fmaxf(acc[r] + bsv, 0.f));
      eB[(mt * 16 + quad * 4 + r) * 72 + nCol] = f2b(e);
    }
  }
  __syncthreads();

  // ---- phase 2: lane = channel, wave picks pillars round-robin -------------
  const int c = lane;
  const int pfirst = idx[plist[w0]];
  const int plast  = idx[plist[w1 - 1]];
  for (int p = pfirst + wv; p <= plast; p += 4) {
    const int pb = off[p], pe = off[p + 1];
    const int l2 = max(pb, w0) - w0;
    const int h2 = min(pe, w1) - w0;
    if (h2 <= l2) continue;
    float dn = 0.f, nm = 0.f, hm = 0.f;
    for (int r = l2; r < h2; ++r) {
      const float hv = b2f(hB[r * 72 + c]);
      const float ev = b2f(eB[r * 72 + c]);
      dn += ev;
      nm = fmaf(hv, ev, nm);
      hm = fmaxf(hm, hv);
    }
    const size_t o = (size_t)p * CH + c;
    if (pb >= w0 && pe <= w1) {          // sole writer: plain stores
      num[o] = nm; den[o] = dn; hmx[o] = hm;
    } else {                              // window-boundary pillar: accumulate
      atomicAdd(num + o, nm);
      atomicAdd(den + o, dn);
      atomicMax((int*)hmx + o, __float_as_int(hm));  // hm >= 0: int order == float order
    }
  }
}

// ---- canvas gather with fused finalize -------------------------------------
__global__ __launch_bounds__(256)
void k_canvas(const int* __restrict__ inv, const float* __restrict__ num,
              const float* __restrict__ den, const float* __restrict__ hmx,
              float* __restrict__ out) {
  const int t = threadIdx.x;
  const int bid = blockIdx.x;                 // BQ*WBEV*2
  const int half = bid & 1;
  const int x = (bid >> 1) & (WBEV - 1);
  const int b = bid >> 10;
  const int ybase = half * 256;
  const size_t cell = (size_t)b * WH + (size_t)x * HBEV + ybase + t;
  const int iv = inv[cell];
  const size_t obase = (size_t)b * ((size_t)CH * WH) + (size_t)x * HBEV + ybase + t;
  if (iv >= 0) {
    const float4* np = (const float4*)(num + (size_t)iv * CH);
    const float4* dp = (const float4*)(den + (size_t)iv * CH);
    const float4* mp = (const float4*)(hmx + (size_t)iv * CH);
#pragma unroll 4
    for (int cq = 0; cq < 16; ++cq) {
      const float4 n = np[cq], d = dp[cq], m = mp[cq];
      out[obase + (size_t)(4 * cq + 0) * WH] = 0.5f * (n.x / d.x + m.x);
      out[obase + (size_t)(4 * cq + 1) * WH] = 0.5f * (n.y / d.y + m.y);
      out[obase + (size_t)(4 * cq + 2) * WH] = 0.5f * (n.z / d.z + m.z);
      out[obase + (size_t)(4 * cq + 3) * WH] = 0.5f * (n.w / d.w + m.w);
    }
  } else {
#pragma unroll 8
    for (int cc = 0; cc < CH; ++cc) out[obase + (size_t)cc * WH] = 0.f;
  }
}

extern "C" void kernel_launch(void* const* d_in, const int* in_sizes, int n_in,
                              void* d_out, int out_size, void* d_ws, size_t ws_size,
                              hipStream_t stream) {
  const float* X     = (const float*)d_in[0];
  const int*   idx   = (const int*)  d_in[1];
  const int*   pind  = (const int*)  d_in[2];
  const float* W0    = (const float*)d_in[3];
  const float* gamma = (const float*)d_in[4];
  const float* beta  = (const float*)d_in[5];
  const float* Ws    = (const float*)d_in[6];
  const float* bs    = (const float*)d_in[7];
  float* out = (float*)d_out;
  const int N = in_sizes[0] / C_INP;   // 2,000,000
  const int M = in_sizes[2] / 3;       // 200,000
  const int nwin = (N + WIN - 1) / WIN;
  const int nsb  = (M + SCHUNK - 1) / SCHUNK;   // scan blocks (196 <= 256)

  char* p = (char*)d_ws;
  auto carve = [&](size_t bytes) -> char* {
    char* r = p;
    p += (bytes + 255) & ~(size_t)255;
    return r;
  };
  int*   counts = (int*)  carve((size_t)M * 4);
  int*   off    = (int*)  carve((size_t)(M + 1) * 4);
  int*   head   = (int*)  carve((size_t)M * 4);
  int*   plist  = (int*)  carve((size_t)N * 4);
  int*   bsum   = (int*)  carve((size_t)256 * 4);
  float* sums   = (float*)carve(65 * 4);
  float* W0p    = (float*)carve((size_t)C_INP * CH * 4);
  float* b0p    = (float*)carve((size_t)CH * 4);
  float* num    = (float*)carve((size_t)M * CH * 4);
  float* den    = (float*)carve((size_t)M * CH * 4);
  float* hmx    = (float*)carve((size_t)M * CH * 4);
  int*   inv    = (int*)  carve((size_t)BQ * WH * 4);

  hipMemsetAsync(counts, 0, (size_t)M * 4, stream);
  hipMemsetAsync(sums, 0, 65 * 4, stream);
  hipMemsetAsync(inv, 0xFF, (size_t)BQ * WH * 4, stream);   // -1

  k_stats <<<1024, 256, 0, stream>>>(X, N, sums);
  k_bnfold<<<1, 64, 0, stream>>>(sums, W0, gamma, beta, (float)N, W0p, b0p);
  k_count <<<(N + 255) / 256, 256, 0, stream>>>(idx, N, counts);
  k_scan1 <<<nsb, 256, 0, stream>>>(counts, M, bsum);
  k_scan2 <<<1, 256, 0, stream>>>(bsum, nsb);
  k_scan3 <<<nsb, 256, 0, stream>>>(counts, M, N, bsum, off, head);
  k_fill  <<<(N + 255) / 256, 256, 0, stream>>>(idx, N, head, plist);
  k_zb    <<<nwin, 64, 0, stream>>>(idx, plist, N, num, den, hmx);
  k_invmap<<<(M + 255) / 256, 256, 0, stream>>>(pind, M, inv);
  k_main  <<<nwin, 256, 0, stream>>>(X, plist, idx, off, W0p, b0p,
                                     Ws, bs, num, den, hmx, N, M);
  k_canvas<<<BQ * WBEV * 2, 256, 0, stream>>>(inv, num, den, hmx, out);
}

// Round 6
// 930.238 us; speedup vs baseline: 3.7187x; 1.0400x over previous
//
#include <hip/hip_runtime.h>
#include <stdint.h>

#define C_INP 10
#define CH    64
#define WBEV  512
#define HBEV  512
#define BQ    4
#define WH    (WBEV*HBEV)
#define BN_EPS 1e-3f
#define WIN   160     // points per k_main block (LDS: 2*160*72*2 = 46080 B -> 3 blocks/CU)
#define TILES (WIN/16)
#define SCHUNK 1024   // counts per scan block

typedef unsigned short ushort8 __attribute__((ext_vector_type(8)));
typedef short  bf16x8 __attribute__((ext_vector_type(8)));
typedef float  f32x4  __attribute__((ext_vector_type(4)));

__device__ __forceinline__ unsigned short f2b(float x) {   // fp32 -> bf16 RNE
  unsigned int u = __float_as_uint(x);
  return (unsigned short)((u + 0x7FFFu + ((u >> 16) & 1u)) >> 16);
}
__device__ __forceinline__ float b2f(unsigned short u) {
  return __uint_as_float(((unsigned int)u) << 16);
}

// ---- Pass 1: X moments (65 acc) + pillar counts (fused) ---------------------
__global__ __launch_bounds__(256, 1)
void k_stats(const float* __restrict__ X, const int* __restrict__ idx, int N,
             float* __restrict__ sums, int* __restrict__ counts) {
  float a[65];
#pragma unroll
  for (int i = 0; i < 65; ++i) a[i] = 0.f;
  const int stride = gridDim.x * blockDim.x;
  for (int i = blockIdx.x * blockDim.x + threadIdx.x; i < N; i += stride) {
    const float* xr = X + (size_t)i * C_INP;
    float x[C_INP];
#pragma unroll
    for (int k = 0; k < C_INP; k += 2) {
      const float2 v = *(const float2*)(xr + k);
      x[k] = v.x; x[k + 1] = v.y;
    }
    atomicAdd(&counts[idx[i]], 1);
#pragma unroll
    for (int k = 0; k < C_INP; ++k) a[k] += x[k];
#pragma unroll
    for (int k = 0; k < C_INP; ++k)
#pragma unroll
      for (int l = k; l < C_INP; ++l)
        a[C_INP + (k * (21 - k)) / 2 + (l - k)] = fmaf(x[k], x[l], a[C_INP + (k * (21 - k)) / 2 + (l - k)]);
  }
  __shared__ float red[4 * 65];
  const int wv = threadIdx.x >> 6;
#pragma unroll
  for (int i = 0; i < 65; ++i) {
    float v = a[i];
    v += __shfl_down(v, 32, 64);
    v += __shfl_down(v, 16, 64);
    v += __shfl_down(v, 8, 64);
    v += __shfl_down(v, 4, 64);
    v += __shfl_down(v, 2, 64);
    v += __shfl_down(v, 1, 64);
    if ((threadIdx.x & 63) == 0) red[wv * 65 + i] = v;
  }
  __syncthreads();
  const int t = threadIdx.x;
  if (t < 65) atomicAdd(&sums[t], red[t] + red[65 + t] + red[130 + t] + red[195 + t]);
}

// ---- Fold BN into W0', b0' --------------------------------------------------
__global__ void k_bnfold(const float* __restrict__ sums, const float* __restrict__ W0,
                         const float* __restrict__ gamma, const float* __restrict__ beta,
                         float Nf, float* __restrict__ W0p, float* __restrict__ b0p) {
  const int c = threadIdx.x;  // 64
  float w[C_INP];
#pragma unroll
  for (int k = 0; k < C_INP; ++k) w[k] = W0[k * CH + c];
  float mu = 0.f;
#pragma unroll
  for (int k = 0; k < C_INP; ++k) mu += (sums[k] / Nf) * w[k];
  float ex2 = 0.f;
  int ti = C_INP;
#pragma unroll
  for (int k = 0; k < C_INP; ++k)
#pragma unroll
    for (int l = k; l < C_INP; ++l) {
      const float s = sums[ti++] / Nf;
      ex2 += (k == l ? w[k] * w[k] : 2.f * w[k] * w[l]) * s;
    }
  const float var = ex2 - mu * mu;
  const float sc = gamma[c] * rsqrtf(var + BN_EPS);
#pragma unroll
  for (int k = 0; k < C_INP; ++k) W0p[k * CH + c] = w[k] * sc;
  b0p[c] = beta[c] - mu * sc;
}

// ---- pack W0'/bias and Ws into MFMA B-fragment order (bf16) -----------------
// w0f[tile][lane][8]: B[k=quad*8+j][n=tile*16+l15]; row 10 = bias, rows 11..31 = 0
// wsf[half][tile][lane][8]: Ws B-frags for k-halves 0..31 / 32..63
__global__ __launch_bounds__(256)
void k_pack(const float* __restrict__ W0p, const float* __restrict__ b0p,
            const float* __restrict__ Ws,
            unsigned short* __restrict__ w0f, unsigned short* __restrict__ wsf) {
  const int t = threadIdx.x;
  const int lane = t & 63, tile = t >> 6;
  const int quad = lane >> 4, l15 = lane & 15;
  const int col = tile * 16 + l15;
#pragma unroll
  for (int j = 0; j < 8; ++j) {
    const int k = quad * 8 + j;
    const float v = (k < C_INP) ? W0p[k * CH + col] : (k == C_INP ? b0p[col] : 0.f);
    w0f[(tile * 64 + lane) * 8 + j] = f2b(v);
  }
#pragma unroll
  for (int half = 0; half < 2; ++half)
#pragma unroll
    for (int j = 0; j < 8; ++j) {
      const int k = half * 32 + quad * 8 + j;
      wsf[((half * 4 + tile) * 64 + lane) * 8 + j] = f2b(Ws[k * CH + col]);
    }
}

// ---- multi-block exclusive scan of counts -> off/head; zero straddlers ------
__global__ __launch_bounds__(256)
void k_scan1(const int* __restrict__ counts, int M, int* __restrict__ bsum) {
  __shared__ int lds[256];
  const int b = blockIdx.x, t = threadIdx.x;
  const int base = b * SCHUNK + t * 4;
  int s = 0;
  if (base + 3 < M) {
    const int4 v = *(const int4*)(counts + base);
    s = v.x + v.y + v.z + v.w;
  } else {
#pragma unroll
    for (int j = 0; j < 4; ++j) if (base + j < M) s += counts[base + j];
  }
  lds[t] = s;
  __syncthreads();
  for (int o = 1; o < 256; o <<= 1) {
    const int u = (t >= o) ? lds[t - o] : 0;
    __syncthreads();
    lds[t] += u;
    __syncthreads();
  }
  if (t == 255) bsum[b] = lds[255];
}

__global__ __launch_bounds__(256)
void k_scan2(int* __restrict__ bsum, int nsb) {
  __shared__ int lds[256];
  const int t = threadIdx.x;
  const int v = (t < nsb) ? bsum[t] : 0;
  lds[t] = v;
  __syncthreads();
  for (int o = 1; o < 256; o <<= 1) {
    const int u = (t >= o) ? lds[t - o] : 0;
    __syncthreads();
    lds[t] += u;
    __syncthreads();
  }
  if (t < nsb) bsum[t] = lds[t] - v;   // exclusive base per scan block
}

__global__ __launch_bounds__(256)
void k_scan3(const int* __restrict__ counts, int M, int N,
             const int* __restrict__ bsum,
             int* __restrict__ off, int* __restrict__ head,
             float* __restrict__ nda) {
  __shared__ int lds[256];
  const int b = blockIdx.x, t = threadIdx.x;
  const int base = b * SCHUNK + t * 4;
  int c0 = 0, c1 = 0, c2 = 0, c3 = 0;
  const bool full = (base + 3 < M);
  if (full) {
    const int4 v = *(const int4*)(counts + base);
    c0 = v.x; c1 = v.y; c2 = v.z; c3 = v.w;
  } else {
    if (base     < M) c0 = counts[base];
    if (base + 1 < M) c1 = counts[base + 1];
    if (base + 2 < M) c2 = counts[base + 2];
    if (base + 3 < M) c3 = counts[base + 3];
  }
  const int s = c0 + c1 + c2 + c3;
  lds[t] = s;
  __syncthreads();
  for (int o = 1; o < 256; o <<= 1) {
    const int u = (t >= o) ? lds[t - o] : 0;
    __syncthreads();
    lds[t] += u;
    __syncthreads();
  }
  const int run = bsum[b] + lds[t] - s;
  const int4 ov = {run, run + c0, run + c0 + c1, run + c0 + c1 + c2};
  if (full) {
    *(int4*)(off  + base) = ov;
    *(int4*)(head + base) = ov;
  } else {
    if (base     < M) { off[base]     = ov.x; head[base]     = ov.x; }
    if (base + 1 < M) { off[base + 1] = ov.y; head[base + 1] = ov.y; }
    if (base + 2 < M) { off[base + 2] = ov.z; head[base + 2] = ov.z; }
  }
  if (b == 0 && t == 0) off[M] = N;
  // zero rows of pillars that straddle a window boundary (k_main atomic targets)
  const int st[4] = {ov.x, ov.y, ov.z, ov.w};
  const int cn[4] = {c0, c1, c2, c3};
#pragma unroll
  for (int q = 0; q < 4; ++q) {
    if (base + q < M && cn[q] > 0 && (st[q] / WIN) != ((st[q] + cn[q] - 1) / WIN)) {
      float4* z = (float4*)(nda + (size_t)(base + q) * 192);
      const float4 zz = {0.f, 0.f, 0.f, 0.f};
#pragma unroll
      for (int j = 0; j < 48; ++j) z[j] = zz;
    }
  }
}

__global__ void k_fill(const int* __restrict__ idx, int N, int* __restrict__ head,
                       int* __restrict__ plist) {
  const int i = blockIdx.x * 256 + threadIdx.x;
  if (i < N) {
    const int p = idx[i];
    const int pos = atomicAdd(&head[p], 1);
    plist[pos] = i;
  }
}

// ---- inverse map cell -> pillar --------------------------------------------
__global__ void k_invmap(const int* __restrict__ pind, int M, int* __restrict__ inv) {
  const int p = blockIdx.x * 256 + threadIdx.x;
  if (p < M) {
    const int b = pind[3 * p], x = pind[3 * p + 1], y = pind[3 * p + 2];
    inv[(size_t)b * WH + x * HBEV + y] = p;
  }
}

// ---- main fused kernel: h (MFMA), s=h@Ws (MFMA), exp, per-pillar reductions -
__global__ __launch_bounds__(256, 3)
void k_main(const float* __restrict__ X,
            const int* __restrict__ plist, const int* __restrict__ idx,
            const int* __restrict__ off,
            const unsigned short* __restrict__ w0f,
            const unsigned short* __restrict__ wsf,
            const float* __restrict__ bs,
            float* __restrict__ nda, int N, int M) {
  __shared__ __attribute__((aligned(16))) unsigned short sm[2 * WIN * 72];
  unsigned short* hB = sm;               // [WIN][72] bf16 h
  unsigned short* eB = sm + WIN * 72;    // [WIN][72] bf16 e=exp(relu(s))
  const int t = threadIdx.x;
  const int w0 = blockIdx.x * WIN;
  const int w1 = min(w0 + WIN, N);
  const int wv = t >> 6, lane = t & 63;
  const int l15 = lane & 15, quad = (lane >> 4) & 3;

  // ---- phase 1a: h = relu([X,1] @ [W0';b0']) via MFMA, all waves -----------
  const bf16x8 w0b0 = *(const bf16x8*)(w0f + (0 * 64 + lane) * 8);
  const bf16x8 w0b1 = *(const bf16x8*)(w0f + (1 * 64 + lane) * 8);
  const bf16x8 w0b2 = *(const bf16x8*)(w0f + (2 * 64 + lane) * 8);
  const bf16x8 w0b3 = *(const bf16x8*)(w0f + (3 * 64 + lane) * 8);
  for (int mt = wv; mt < TILES; mt += 4) {
    const int row = mt * 16 + l15;
    const int gi = min(w0 + row, N - 1);
    const int pid = plist[gi];
    const float* xr = X + (size_t)pid * C_INP;
    bf16x8 af = {0, 0, 0, 0, 0, 0, 0, 0};
    if (quad == 0) {
      const float2 p0 = *(const float2*)(xr);
      const float2 p1 = *(const float2*)(xr + 2);
      const float2 p2 = *(const float2*)(xr + 4);
      const float2 p3 = *(const float2*)(xr + 6);
      af[0] = (short)f2b(p0.x); af[1] = (short)f2b(p0.y);
      af[2] = (short)f2b(p1.x); af[3] = (short)f2b(p1.y);
      af[4] = (short)f2b(p2.x); af[5] = (short)f2b(p2.y);
      af[6] = (short)f2b(p3.x); af[7] = (short)f2b(p3.y);
    } else if (quad == 1) {
      const float2 p4 = *(const float2*)(xr + 8);
      af[0] = (short)f2b(p4.x); af[1] = (short)f2b(p4.y);
      af[2] = (short)0x3F80;   // 1.0 -> picks up bias row of B
    }
    f32x4 a0 = {0.f, 0.f, 0.f, 0.f}, a1 = a0, a2 = a0, a3 = a0;
    a0 = __builtin_amdgcn_mfma_f32_16x16x32_bf16(af, w0b0, a0, 0, 0, 0);
    a1 = __builtin_amdgcn_mfma_f32_16x16x32_bf16(af, w0b1, a1, 0, 0, 0);
    a2 = __builtin_amdgcn_mfma_f32_16x16x32_bf16(af, w0b2, a2, 0, 0, 0);
    a3 = __builtin_amdgcn_mfma_f32_16x16x32_bf16(af, w0b3, a3, 0, 0, 0);
#pragma unroll
    for (int r = 0; r < 4; ++r) {
      unsigned short* hr = hB + (mt * 16 + quad * 4 + r) * 72 + l15;
      hr[0]  = f2b(fmaxf(a0[r], 0.f));
      hr[16] = f2b(fmaxf(a1[r], 0.f));
      hr[32] = f2b(fmaxf(a2[r], 0.f));
      hr[48] = f2b(fmaxf(a3[r], 0.f));
    }
  }

  // ---- Ws B-fragments for this wave's channel tile (prepacked) -------------
  const bf16x8 bf0 = *(const bf16x8*)(wsf + ((0 * 4 + wv) * 64 + lane) * 8);
  const bf16x8 bf1 = *(const bf16x8*)(wsf + ((1 * 4 + wv) * 64 + lane) * 8);
  const int nCol = wv * 16 + l15;
  const float bsv = bs[nCol];
  __syncthreads();

  // ---- phase 1b: s = h @ Ws via MFMA; e = exp(relu(s + bs)) -> eB ----------
#pragma unroll 2
  for (int mt = 0; mt < TILES; ++mt) {
    const bf16x8 A0 = *(const bf16x8*)(hB + (mt * 16 + l15) * 72 + quad * 8);
    const bf16x8 A1 = *(const bf16x8*)(hB + (mt * 16 + l15) * 72 + 32 + quad * 8);
    f32x4 acc = {0.f, 0.f, 0.f, 0.f};
    acc = __builtin_amdgcn_mfma_f32_16x16x32_bf16(A0, bf0, acc, 0, 0, 0);
    acc = __builtin_amdgcn_mfma_f32_16x16x32_bf16(A1, bf1, acc, 0, 0, 0);
#pragma unroll
    for (int r = 0; r < 4; ++r) {
      const float e = __expf(fmaxf(acc[r] + bsv, 0.f));
      eB[(mt * 16 + quad * 4 + r) * 72 + nCol] = f2b(e);
    }
  }
  __syncthreads();

  // ---- phase 2: lane = channel, wave picks pillars round-robin -------------
  const int c = lane;
  const int pfirst = idx[plist[w0]];
  const int plast  = idx[plist[w1 - 1]];
  for (int p = pfirst + wv; p <= plast; p += 4) {
    const int pb = off[p], pe = off[p + 1];
    const int l2 = max(pb, w0) - w0;
    const int h2 = min(pe, w1) - w0;
    if (h2 <= l2) continue;
    float dn = 0.f, nm = 0.f, hm = 0.f;
    for (int r = l2; r < h2; ++r) {
      const float hv = b2f(hB[r * 72 + c]);
      const float ev = b2f(eB[r * 72 + c]);
      dn += ev;
      nm = fmaf(hv, ev, nm);
      hm = fmaxf(hm, hv);
    }
    float* row = nda + (size_t)p * 192;
    if (pb >= w0 && pe <= w1) {          // sole writer: plain stores
      row[c] = nm; row[64 + c] = dn; row[128 + c] = hm;
    } else {                              // straddler (pre-zeroed): accumulate
      atomicAdd(row + c, nm);
      atomicAdd(row + 64 + c, dn);
      atomicMax((int*)row + 128 + c, __float_as_int(hm));  // hm >= 0
    }
  }
}

// ---- canvas gather with fused finalize -------------------------------------
__global__ __launch_bounds__(256)
void k_canvas(const int* __restrict__ inv, const float* __restrict__ nda,
              float* __restrict__ out) {
  const int t = threadIdx.x;
  const int bid = blockIdx.x;                 // BQ*WBEV*2
  const int half = bid & 1;
  const int x = (bid >> 1) & (WBEV - 1);
  const int b = bid >> 10;
  const int ybase = half * 256;
  const size_t cell = (size_t)b * WH + (size_t)x * HBEV + ybase + t;
  const int iv = inv[cell];
  const size_t obase = (size_t)b * ((size_t)CH * WH) + (size_t)x * HBEV + ybase + t;
  if (iv >= 0) {
    const float4* np = (const float4*)(nda + (size_t)iv * 192);
    const float4* dp = np + 16;
    const float4* mp = np + 32;
#pragma unroll 4
    for (int cq = 0; cq < 16; ++cq) {
      const float4 n = np[cq], d = dp[cq], m = mp[cq];
      out[obase + (size_t)(4 * cq + 0) * WH] = 0.5f * (n.x / d.x + m.x);
      out[obase + (size_t)(4 * cq + 1) * WH] = 0.5f * (n.y / d.y + m.y);
      out[obase + (size_t)(4 * cq + 2) * WH] = 0.5f * (n.z / d.z + m.z);
      out[obase + (size_t)(4 * cq + 3) * WH] = 0.5f * (n.w / d.w + m.w);
    }
  } else {
#pragma unroll 8
    for (int cc = 0; cc < CH; ++cc) out[obase + (size_t)cc * WH] = 0.f;
  }
}

extern "C" void kernel_launch(void* const* d_in, const int* in_sizes, int n_in,
                              void* d_out, int out_size, void* d_ws, size_t ws_size,
                              hipStream_t stream) {
  const float* X     = (const float*)d_in[0];
  const int*   idx   = (const int*)  d_in[1];
  const int*   pind  = (const int*)  d_in[2];
  const float* W0    = (const float*)d_in[3];
  const float* gamma = (const float*)d_in[4];
  const float* beta  = (const float*)d_in[5];
  const float* Ws    = (const float*)d_in[6];
  const float* bs    = (const float*)d_in[7];
  float* out = (float*)d_out;
  const int N = in_sizes[0] / C_INP;   // 2,000,000
  const int M = in_sizes[2] / 3;       // 200,000
  const int nwin = (N + WIN - 1) / WIN;
  const int nsb  = (M + SCHUNK - 1) / SCHUNK;   // scan blocks (196 <= 256)

  char* p = (char*)d_ws;
  auto carve = [&](size_t bytes) -> char* {
    char* r = p;
    p += (bytes + 255) & ~(size_t)255;
    return r;
  };
  int*   counts = (int*)  carve((size_t)M * 4);
  int*   off    = (int*)  carve((size_t)(M + 1) * 4);
  int*   head   = (int*)  carve((size_t)M * 4);
  int*   plist  = (int*)  carve((size_t)N * 4);
  int*   bsum   = (int*)  carve((size_t)256 * 4);
  float* sums   = (float*)carve(65 * 4);
  float* W0p    = (float*)carve((size_t)C_INP * CH * 4);
  float* b0p    = (float*)carve((size_t)CH * 4);
  unsigned short* w0f = (unsigned short*)carve((size_t)4 * 64 * 8 * 2);
  unsigned short* wsf = (unsigned short*)carve((size_t)8 * 64 * 8 * 2);
  float* nda    = (float*)carve((size_t)M * 192 * 4);   // [M][num|den|hmx]
  int*   inv    = (int*)  carve((size_t)BQ * WH * 4);

  hipMemsetAsync(counts, 0, (size_t)M * 4, stream);
  hipMemsetAsync(sums, 0, 65 * 4, stream);
  hipMemsetAsync(inv, 0xFF, (size_t)BQ * WH * 4, stream);   // -1

  k_stats <<<1024, 256, 0, stream>>>(X, idx, N, sums, counts);
  k_bnfold<<<1, 64, 0, stream>>>(sums, W0, gamma, beta, (float)N, W0p, b0p);
  k_pack  <<<1, 256, 0, stream>>>(W0p, b0p, Ws, w0f, wsf);
  k_scan1 <<<nsb, 256, 0, stream>>>(counts, M, bsum);
  k_scan2 <<<1, 256, 0, stream>>>(bsum, nsb);
  k_scan3 <<<nsb, 256, 0, stream>>>(counts, M, N, bsum, off, head, nda);
  k_fill  <<<(N + 255) / 256, 256, 0, stream>>>(idx, N, head, plist);
  k_invmap<<<(M + 255) / 256, 256, 0, stream>>>(pind, M, inv);
  k_main  <<<nwin, 256, 0, stream>>>(X, plist, idx, off, w0f, wsf, bs, nda, N, M);
  k_canvas<<<BQ * WBEV * 2, 256, 0, stream>>>(inv, nda, out);
}